// Round 1
// baseline (278.186 us; speedup 1.0000x reference)
//
#include <hip/hip_runtime.h>
#include <cstdint>
#include <cstddef>

// Problem constants
#define M_DIM 8192   // batch
#define N_DIM 256    // shared rows (distinct output cols)
#define K_DIM 4096   // in_features
#define OUT_F 4096   // out_features = 16 * N_DIM
// Fused GEMM tiling
#define BM 32        // m-rows per block -> grid 256 = 1 block/CU
#define BK 64        // k per tile
#define NTH 512      // 8 waves; wave w owns 32m x 32n (Rm=1: zero B redundancy)
#define LDK 72       // padded LDS K-stride (halves); 144 B = 16B-aligned, 2-way-only aliasing

typedef float    float4_  __attribute__((ext_vector_type(4)));
typedef _Float16 half8    __attribute__((ext_vector_type(8)));
typedef _Float16 half4    __attribute__((ext_vector_type(4)));

// ---------------------------------------------------------------------------
// Kernel 1: convert shared_weights fp32 -> f16 into workspace (2 MB).
// W f16 stays L2-resident; the fused kernel reads B-frags straight from it.
// ---------------------------------------------------------------------------
__global__ __launch_bounds__(256) void convert_w_kernel(const float* __restrict__ w,
                                                        _Float16* __restrict__ wh) {
  int i = (blockIdx.x * 256 + threadIdx.x) * 8;
  float4_ f0 = *(const float4_*)(w + i);
  float4_ f1 = *(const float4_*)(w + i + 4);
  half8 h;
  h[0] = (_Float16)f0[0]; h[1] = (_Float16)f0[1];
  h[2] = (_Float16)f0[2]; h[3] = (_Float16)f0[3];
  h[4] = (_Float16)f1[0]; h[5] = (_Float16)f1[1];
  h[6] = (_Float16)f1[2]; h[7] = (_Float16)f1[3];
  *(half8*)(wh + i) = h;
}

// ---------------------------------------------------------------------------
// Fused kernel: S = x @ W^T (f16 MFMA, B-frags direct from L2, A via LDS),
// then epilogue expands S 16x with bias straight to out. No P partials.
// ---------------------------------------------------------------------------
__device__ __forceinline__ void load_bfrag(half8 b[2][2],
                                           const _Float16* __restrict__ wg0,
                                           const _Float16* __restrict__ wg1,
                                           int kk) {
#pragma unroll
  for (int ks = 0; ks < 2; ++ks) {
    b[ks][0] = *(const half8*)(wg0 + kk + ks * 32);
    b[ks][1] = *(const half8*)(wg1 + kk + ks * 32);
  }
}

__device__ __forceinline__ void stage_a(_Float16 (*As)[LDK], int arow, int acol,
                                        float4_ a) {
  half4 h;
  h[0] = (_Float16)a[0]; h[1] = (_Float16)a[1];
  h[2] = (_Float16)a[2]; h[3] = (_Float16)a[3];
  *(half4*)(&As[arow][acol]) = h;
}

__device__ __forceinline__ void mfma_step(float4_ acc[2][2], const half8 b[2][2],
                                          const _Float16 (*As)[LDK],
                                          int l16, int quad) {
#pragma unroll
  for (int ks = 0; ks < 2; ++ks) {
    const int koff = ks * 32 + quad * 8;
    half8 a0 = *(const half8*)(&As[l16][koff]);
    half8 a1 = *(const half8*)(&As[16 + l16][koff]);
    acc[0][0] = __builtin_amdgcn_mfma_f32_16x16x32_f16(a0, b[ks][0], acc[0][0], 0, 0, 0);
    acc[1][0] = __builtin_amdgcn_mfma_f32_16x16x32_f16(a1, b[ks][0], acc[1][0], 0, 0, 0);
    acc[0][1] = __builtin_amdgcn_mfma_f32_16x16x32_f16(a0, b[ks][1], acc[0][1], 0, 0, 0);
    acc[1][1] = __builtin_amdgcn_mfma_f32_16x16x32_f16(a1, b[ks][1], acc[1][1], 0, 0, 0);
  }
}

__global__ __launch_bounds__(NTH, 2) void fused_kernel(const float* __restrict__ x,
                                                       const _Float16* __restrict__ wh,
                                                       const float* __restrict__ bias,
                                                       float* __restrict__ out) {
  __shared__ __align__(16) _Float16 As[2][BM][LDK];   //  9216 B, double-buffered
  __shared__ __align__(16) float Ssh[BM][N_DIM + 4];  // 33280 B (pad 4 breaks 1KB stride)
  __shared__ __align__(16) float bsh[OUT_F];          // 16384 B   (total 58880)

  const int tid  = threadIdx.x;
  const int wv   = tid >> 6;        // 0..7
  const int lane = tid & 63;
  const int quad = lane >> 4;       // 0..3
  const int l16  = lane & 15;
  const int n0   = wv * 32;         // wave n-slice base (Rm=1: 8 n-groups)
  const int m0   = blockIdx.x * BM;

  // ---- bias -> LDS (read only after K-loop; its barriers order this) ----
  {
    const float4_* b4 = (const float4_*)bias;
    float4_* bs4 = (float4_*)bsh;
    bs4[tid] = b4[tid];
    bs4[NTH + tid] = b4[NTH + tid];
  }

  // ---- A staging coords: 32 rows x 64 f32 per kt; 512 thr x 4 floats ----
  const int arow = tid >> 4;          // 0..31
  const int acol = (tid & 15) * 4;    // 0..60
  const float* xg = x + (size_t)(m0 + arow) * K_DIM + acol;

  // ---- B-frag pointers (per-lane, direct from L2-resident wh) ----
  const _Float16* wg0 = wh + (size_t)(n0 + l16) * K_DIM + quad * 8;
  const _Float16* wg1 = wg0 + (size_t)16 * K_DIM;

  float4_ acc[2][2];
  const float4_ fzero = {0.f, 0.f, 0.f, 0.f};
#pragma unroll
  for (int i = 0; i < 2; ++i)
#pragma unroll
    for (int j = 0; j < 2; ++j) acc[i][j] = fzero;

  // ---- prologue: x 2-kt ahead (HBM latency), B 1-kt ahead (L2 latency) ----
  half8 bA[2][2], bB[2][2];
  float4_ aP0 = __builtin_nontemporal_load((const float4_*)(xg));
  float4_ aP1 = __builtin_nontemporal_load((const float4_*)(xg + BK));
  load_bfrag(bA, wg0, wg1, 0);
  stage_a(As[0], arow, acol, aP0);
  aP0 = __builtin_nontemporal_load((const float4_*)(xg + 2 * BK));
  __syncthreads();  // As[0] ready

  const int NKT = K_DIM / BK;  // 64 (even)
  for (int kt = 0; kt < NKT; kt += 2) {
    // even: compute kt (As[0], bA); stage kt+1 -> As[1]
    load_bfrag(bB, wg0, wg1, (kt + 1) * BK);
    stage_a(As[1], arow, acol, aP1);
    if (kt + 3 < NKT)
      aP1 = __builtin_nontemporal_load((const float4_*)(xg + (kt + 3) * BK));
    mfma_step(acc, bA, As[0], l16, quad);
    __syncthreads();  // As[1] ready, As[0] free

    // odd: compute kt+1 (As[1], bB); stage kt+2 -> As[0]
    if (kt + 2 < NKT) {
      load_bfrag(bA, wg0, wg1, (kt + 2) * BK);
      stage_a(As[0], arow, acol, aP0);
      if (kt + 4 < NKT)
        aP0 = __builtin_nontemporal_load((const float4_*)(xg + (kt + 4) * BK));
    }
    mfma_step(acc, bB, As[1], l16, quad);
    __syncthreads();  // As[0] ready, As[1] free
  }

  // ---- epilogue 1: S-tile -> LDS (C/D layout: n=l16, m=quad*4+r) ----
#pragma unroll
  for (int mf = 0; mf < 2; ++mf)
#pragma unroll
    for (int nf = 0; nf < 2; ++nf)
#pragma unroll
      for (int r = 0; r < 4; ++r)
        Ssh[mf * 16 + quad * 4 + r][n0 + nf * 16 + l16] = acc[mf][nf][r];
  __syncthreads();

  // ---- epilogue 2: stream out = S[m][j&255] + bias[j], 1 KB/wave stores ----
  float4_ s[4];
#pragma unroll
  for (int rr = 0; rr < 4; ++rr)
    s[rr] = *(const float4_*)(&Ssh[wv * 4 + rr][lane * 4]);

  float4_* o0 = (float4_*)(out + (size_t)(m0 + wv * 4) * OUT_F);
  const float4_* bs4 = (const float4_*)bsh;
#pragma unroll
  for (int i = 0; i < 16; ++i) {
    float4_ b4 = bs4[i * 64 + lane];
#pragma unroll
    for (int rr = 0; rr < 4; ++rr)
      __builtin_nontemporal_store(s[rr] + b4,
                                  o0 + (size_t)rr * (OUT_F / 4) + i * 64 + lane);
  }
}

// ---------------------------------------------------------------------------
extern "C" void kernel_launch(void* const* d_in, const int* in_sizes, int n_in,
                              void* d_out, int out_size, void* d_ws, size_t ws_size,
                              hipStream_t stream) {
  const float* x    = (const float*)d_in[0];
  const float* w    = (const float*)d_in[1];
  const float* bias = (const float*)d_in[2];
  float* out        = (float*)d_out;
  _Float16* wh      = (_Float16*)d_ws;  // 2 MB only (no P partials anymore)

  convert_w_kernel<<<(N_DIM * K_DIM) / (256 * 8), 256, 0, stream>>>(w, wh);
  fused_kernel<<<M_DIM / BM, NTH, 0, stream>>>(x, wh, bias, out);
}

// Round 2
// 270.559 us; speedup vs baseline: 1.0282x; 1.0282x over previous
//
#include <hip/hip_runtime.h>
#include <cstdint>
#include <cstddef>

// Problem constants
#define M_DIM 8192   // batch
#define N_DIM 256    // shared rows (distinct output cols)
#define K_DIM 4096   // in_features
#define OUT_F 4096   // out_features = 16 * N_DIM
// Fused GEMM tiling
#define BM 32        // m-rows per block
#define BN 128       // n-half per block -> grid (256,2) = 512 blocks = 2/CU
#define BK 64        // k per tile
#define NTH 512      // 8 waves; wave w owns 32m x 16n (Rm=1: zero B redundancy)

typedef float    float4_  __attribute__((ext_vector_type(4)));
typedef _Float16 half8    __attribute__((ext_vector_type(8)));
typedef _Float16 half4    __attribute__((ext_vector_type(4)));

// ---------------------------------------------------------------------------
// Kernel 1: convert shared_weights fp32 -> f16 into workspace (2 MB).
// W f16 stays L2-resident; the fused kernel reads B-frags straight from it.
// ---------------------------------------------------------------------------
__global__ __launch_bounds__(256) void convert_w_kernel(const float* __restrict__ w,
                                                        _Float16* __restrict__ wh) {
  int i = (blockIdx.x * 256 + threadIdx.x) * 8;
  float4_ f0 = *(const float4_*)(w + i);
  float4_ f1 = *(const float4_*)(w + i + 4);
  half8 h;
  h[0] = (_Float16)f0[0]; h[1] = (_Float16)f0[1];
  h[2] = (_Float16)f0[2]; h[3] = (_Float16)f0[3];
  h[4] = (_Float16)f1[0]; h[5] = (_Float16)f1[1];
  h[6] = (_Float16)f1[2]; h[7] = (_Float16)f1[3];
  *(half8*)(wh + i) = h;
}

// ---------------------------------------------------------------------------
// Fused kernel: S = x @ W^T (f16 MFMA, B-frags direct from L2, A via LDS with
// XOR-swizzled linear layout), epilogue expands S 16x with bias -> out.
// 2 blocks/CU: independent barrier groups overlap; read/write phases mix.
// ---------------------------------------------------------------------------
__device__ __forceinline__ void load_bfrag(half8 b[2], const _Float16* __restrict__ wg,
                                           int kk) {
  b[0] = *(const half8*)(wg + kk);
  b[1] = *(const half8*)(wg + kk + 32);
}

// A tile [32][64] halves, linear, 16B-granule XOR swizzle: granule g at row r
// stored at g ^ (r&7). Row stride 128 B (0 mod 32 banks) -> swizzle spreads
// rows across all 8 granule-slots; both write (half4) and read (half8) are
// bank-uniform (8 lanes / 4-bank slot = the b128 floor).
__device__ __forceinline__ void stage_a(_Float16* __restrict__ As, int arow, int asw,
                                        float4_ a) {
  half4 h;
  h[0] = (_Float16)a[0]; h[1] = (_Float16)a[1];
  h[2] = (_Float16)a[2]; h[3] = (_Float16)a[3];
  *(half4*)(As + arow * BK + asw) = h;
}

__device__ __forceinline__ void mfma_step(float4_ acc[2], const half8 b[2],
                                          const _Float16* __restrict__ As,
                                          int l16, int quad) {
#pragma unroll
  for (int ks = 0; ks < 2; ++ks) {
    const int off = ((ks * 4 + quad) ^ (l16 & 7)) << 3;  // swizzled k-granule
    half8 a0 = *(const half8*)(As + l16 * BK + off);
    half8 a1 = *(const half8*)(As + (16 + l16) * BK + off);
    acc[0] = __builtin_amdgcn_mfma_f32_16x16x32_f16(a0, b[ks], acc[0], 0, 0, 0);
    acc[1] = __builtin_amdgcn_mfma_f32_16x16x32_f16(a1, b[ks], acc[1], 0, 0, 0);
  }
}

__global__ __launch_bounds__(NTH, 4) void fused_kernel(const float* __restrict__ x,
                                                       const _Float16* __restrict__ wh,
                                                       const float* __restrict__ bias,
                                                       float* __restrict__ out) {
  __shared__ __align__(16) _Float16 As[2][BM * BK];   //  8192 B, double-buffered
  __shared__ __align__(16) float Ssh[BM][BN + 4];     // 16896 B (pad 4: 528B stride)
  __shared__ __align__(16) float bsh[16 * BN];        //  8192 B   (total 33280)

  const int tid  = threadIdx.x;
  const int wv   = tid >> 6;        // 0..7
  const int lane = tid & 63;
  const int quad = lane >> 4;       // 0..3
  const int l16  = lane & 15;
  const int m0   = blockIdx.x * BM;
  const int nb   = blockIdx.y * BN; // 0 or 128: this block's W-row half

  // ---- bias -> LDS, rep-major [16][BN] (ordered by K-loop's first barrier) ----
  {
    const float4_* b4 = (const float4_*)bias;
    float4_* bs4 = (float4_*)bsh;
    bs4[tid] = b4[(tid >> 5) * (N_DIM / 4) + (nb >> 2) + (tid & 31)];
  }

  // ---- A staging coords: 32 rows x 64 f32 per kt; 512 thr x 1 float4 ----
  const int arow = tid >> 4;           // 0..31
  const int ac4  = tid & 15;           // float4 index 0..15
  const int asw  = ((((ac4 >> 1) ^ (arow & 7)) << 3) | ((ac4 & 1) << 2));
  const float* xg = x + (size_t)(m0 + arow) * K_DIM + ac4 * 4;

  // ---- B-frag pointer (per-lane, direct from L2-resident wh; Rm=1) ----
  const _Float16* wg = wh + (size_t)(nb + wv * 16 + l16) * K_DIM + quad * 8;

  float4_ acc[2];
  acc[0] = (float4_){0.f, 0.f, 0.f, 0.f};
  acc[1] = (float4_){0.f, 0.f, 0.f, 0.f};

  // ---- prologue: x 2 k-tiles ahead, B 1 k-tile ahead ----
  half8 bA[2], bB[2];
  float4_ aP0 = *(const float4_*)(xg);
  float4_ aP1 = *(const float4_*)(xg + BK);
  load_bfrag(bA, wg, 0);
  stage_a(As[0], arow, asw, aP0);
  aP0 = *(const float4_*)(xg + 2 * BK);
  __syncthreads();  // As[0] ready (also orders bsh)

  const int NKT = K_DIM / BK;  // 64 (even)
  for (int kt = 0; kt < NKT; kt += 2) {
    // even: compute kt (As[0], bA); stage kt+1 -> As[1]
    load_bfrag(bB, wg, (kt + 1) * BK);
    stage_a(As[1], arow, asw, aP1);
    if (kt + 3 < NKT) aP1 = *(const float4_*)(xg + (kt + 3) * BK);
    mfma_step(acc, bA, As[0], l16, quad);
    __syncthreads();  // As[1] ready, As[0] free

    // odd: compute kt+1 (As[1], bB); stage kt+2 -> As[0]
    if (kt + 2 < NKT) {
      load_bfrag(bA, wg, (kt + 2) * BK);
      stage_a(As[0], arow, asw, aP0);
      if (kt + 4 < NKT) aP0 = *(const float4_*)(xg + (kt + 4) * BK);
    }
    mfma_step(acc, bB, As[1], l16, quad);
    __syncthreads();  // As[0] ready, As[1] free
  }

  // ---- epilogue 1: S-tile -> LDS (C/D layout: n=l16, m=quad*4+r) ----
#pragma unroll
  for (int mf = 0; mf < 2; ++mf)
#pragma unroll
    for (int r = 0; r < 4; ++r)
      Ssh[mf * 16 + quad * 4 + r][wv * 16 + l16] = acc[mf][r];
  __syncthreads();

  // ---- epilogue 2: out = S[m][j&255] + bias[j]; 512B/rep coalesced stores ----
  float4_* out4 = (float4_*)out;
  const float4_* bs4 = (const float4_*)bsh;
#pragma unroll
  for (int p = 0; p < 2; ++p) {
    const int row = wv * 4 + p * 2 + (lane >> 5);  // wave owns 4 m-rows
    const int c4  = lane & 31;                     // float4 col within 128-wide
    float4_ sv = *(const float4_*)(&Ssh[row][c4 * 4]);
    const size_t obase = (size_t)(m0 + row) * (OUT_F / 4) + (nb >> 2);
#pragma unroll
    for (int rep = 0; rep < 16; ++rep)
      __builtin_nontemporal_store(sv + bs4[rep * (BN / 4) + c4],
                                  out4 + obase + rep * (N_DIM / 4) + c4);
  }
}

// ---------------------------------------------------------------------------
extern "C" void kernel_launch(void* const* d_in, const int* in_sizes, int n_in,
                              void* d_out, int out_size, void* d_ws, size_t ws_size,
                              hipStream_t stream) {
  const float* x    = (const float*)d_in[0];
  const float* w    = (const float*)d_in[1];
  const float* bias = (const float*)d_in[2];
  float* out        = (float*)d_out;
  _Float16* wh      = (_Float16*)d_ws;  // 2 MB only

  convert_w_kernel<<<(N_DIM * K_DIM) / (256 * 8), 256, 0, stream>>>(w, wh);
  fused_kernel<<<dim3(M_DIM / BM, 2), NTH, 0, stream>>>(x, wh, bias, out);
}